// Round 5
// baseline (175.964 us; speedup 1.0000x reference)
//
#include <hip/hip_runtime.h>
#include <hip/hip_bf16.h>

#define B_ 8
#define T_ 2048
#define E_ 1024
#define D_ 128

typedef __attribute__((ext_vector_type(8))) short short8;
typedef __attribute__((ext_vector_type(4))) short short4v;
typedef __attribute__((ext_vector_type(4))) float floatx4;
typedef __attribute__((ext_vector_type(16))) float floatx16;

__device__ __forceinline__ unsigned short f2b(float f) {
  union { float f; unsigned int u; } v; v.f = f;
  unsigned int u = v.u;
  return (unsigned short)((u + 0x7fffu + ((u >> 16) & 1u)) >> 16);  // RNE
}

#if defined(__has_builtin)
#if __has_builtin(__builtin_amdgcn_exp2f)
#define EXP2F(x) __builtin_amdgcn_exp2f(x)
#else
#define EXP2F(x) exp2f(x)
#endif
#else
#define EXP2F(x) exp2f(x)
#endif

__device__ __forceinline__ void gl_lds16(const unsigned short* g, unsigned short* l) {
  __builtin_amdgcn_global_load_lds(
      (const __attribute__((address_space(1))) unsigned int*)g,
      (__attribute__((address_space(3))) unsigned int*)l, 16, 0, 0);
}

// ---------------------------------------------------------------------------
// Kernel 1: W [1024x128] fp32 -> Wt3 [3][128][1024] bf16 via LDS transpose.
// log2e/sqrt(128) folded into Wq (attn softmax then uses exp2 directly).
// ---------------------------------------------------------------------------
__global__ __launch_bounds__(256) void wtrans_kernel(
    const float* __restrict__ Wq, const float* __restrict__ Wk,
    const float* __restrict__ Wv, unsigned short* __restrict__ Wt3) {
  __shared__ __align__(16) unsigned short Tls[32][136];
  const int tid = threadIdx.x;
  const int w = blockIdx.x >> 5;
  const int rem = blockIdx.x & 31;
  const int k0 = (rem >> 2) * 128;
  const int n0 = (rem & 3) * 32;
  const float* W = (w == 0) ? Wq : ((w == 1) ? Wk : Wv);
  const float scale = (w == 0) ? (1.4426950408889634f * 0.08838834764831845f) : 1.0f;
#pragma unroll
  for (int j = 0; j < 4; j++) {
    int id = tid + 256 * j;
    int k = id >> 3;
    int nn = (id & 7) * 4;
    float4 v = *(const float4*)(W + (size_t)(k0 + k) * D_ + n0 + nn);
    Tls[nn + 0][k] = f2b(v.x * scale);
    Tls[nn + 1][k] = f2b(v.y * scale);
    Tls[nn + 2][k] = f2b(v.z * scale);
    Tls[nn + 3][k] = f2b(v.w * scale);
  }
  __syncthreads();
#pragma unroll
  for (int j = 0; j < 2; j++) {
    int id = tid + 256 * j;
    int n = id >> 4;
    int seg = id & 15;
    short8 o = *(const short8*)&Tls[n][seg * 8];
    *(short8*)&Wt3[(size_t)w * D_ * E_ + (size_t)(n0 + n) * E_ + k0 + seg * 8] = o;
  }
}

// ---------------------------------------------------------------------------
// Kernel 2: fused QKV. Tile 64 tok x 192 ch (grid = 2 ch-groups x 256 token
// tiles = 512 blocks x 256 thr, 34 KB LDS -> 4 blocks/CU). BK=64, 16 iters.
// Halves W-restage L2 traffic vs 32-tok tiles; X read 2x (2nd hits LLC).
// X: reg-prefetch fp32->bf16; W: global_load_lds XOR-swizzled; m97 2-barrier.
// ---------------------------------------------------------------------------
#define XLD 72  // 64 + 8 pad (shorts)

__global__ __launch_bounds__(256) void qkv_kernel(
    const float* __restrict__ X, const unsigned short* __restrict__ Wt3,
    unsigned short* __restrict__ Qb, unsigned short* __restrict__ Kb,
    unsigned short* __restrict__ Vt) {
  __shared__ __align__(16) unsigned short Xs[64 * XLD];   // 9.2 KB
  __shared__ __align__(16) unsigned short Ws[192 * 64];   // 24 KB swizzled
  const int tid = threadIdx.x;
  const int wv = tid >> 6;
  const int lane = tid & 63;
  const int l16 = lane & 15;
  const int quad = lane >> 4;
  const int wm = wv & 1;   // token half
  const int wn = wv >> 1;  // channel half (96 each)

  const int g = blockIdx.x & 1;
  const int m0 = (blockIdx.x >> 1) * 64;
  const unsigned short* Wg = Wt3 + (size_t)g * 192 * E_;

  const int xrow = tid >> 2;        // 0..63
  const int xq = (tid & 3) * 16;    // col group base (floats)
  const int wrow_off = lane >> 3;
  const int wslot = lane & 7;

  floatx4 acc[2][6];
#pragma unroll
  for (int mt = 0; mt < 2; mt++)
#pragma unroll
    for (int nt = 0; nt < 6; nt++) acc[mt][nt] = (floatx4){0.f, 0.f, 0.f, 0.f};

  // prologue: X(0) into regs (4 float4/thread)
  float4 xr[4];
#pragma unroll
  for (int c = 0; c < 4; c++)
    xr[c] = *(const float4*)(X + (size_t)(m0 + xrow) * E_ + xq + c * 4);

  for (int i = 0; i < 16; i++) {
    if (i) __syncthreads();  // compute(i-1) done reading LDS
    const int k0 = i * 64;
    // store prefetched X (converted to bf16)
#pragma unroll
    for (int c = 0; c < 4; c++) {
      ushort4 pk;
      pk.x = f2b(xr[c].x); pk.y = f2b(xr[c].y);
      pk.z = f2b(xr[c].z); pk.w = f2b(xr[c].w);
      *(ushort4*)&Xs[xrow * XLD + xq + c * 4] = pk;
    }
    // W tile 192x64 via glds: 24 insts, 6/wave (8 rows x 8 segs each)
#pragma unroll
    for (int j = 0; j < 6; j++) {
      int rbase = wv * 48 + j * 8;
      int row = rbase + wrow_off;
      int gseg = wslot ^ (row & 7);
      gl_lds16(Wg + (size_t)row * E_ + k0 + gseg * 8, &Ws[rbase * 64]);
    }
    __syncthreads();  // staging visible (vmcnt drain + barrier)
    // prefetch X(i+1)
    if (i < 15) {
#pragma unroll
      for (int c = 0; c < 4; c++)
        xr[c] = *(const float4*)(X + (size_t)(m0 + xrow) * E_ + k0 + 64 + xq + c * 4);
    }
    // compute: 2 mt x 6 nt x 2 kf = 24 MFMA
    short8 af[2][2];
#pragma unroll
    for (int mt = 0; mt < 2; mt++)
#pragma unroll
      for (int kf = 0; kf < 2; kf++)
        af[mt][kf] = *(const short8*)&Xs[(wm * 32 + mt * 16 + l16) * XLD + kf * 32 + quad * 8];
#pragma unroll
    for (int nt = 0; nt < 6; nt++) {
      int n = wn * 96 + nt * 16 + l16;
#pragma unroll
      for (int kf = 0; kf < 2; kf++) {
        short8 bf = *(const short8*)&Ws[n * 64 + ((kf * 4 + quad) ^ (n & 7)) * 8];
        acc[0][nt] = __builtin_amdgcn_mfma_f32_16x16x32_bf16(af[0][kf], bf, acc[0][nt], 0, 0, 0);
        acc[1][nt] = __builtin_amdgcn_mfma_f32_16x16x32_bf16(af[1][kf], bf, acc[1][nt], 0, 0, 0);
      }
    }
  }

  // Epilogue. C/D: col(n)=l16, row(m)=quad*4+r.
#pragma unroll
  for (int mt = 0; mt < 2; mt++)
#pragma unroll
    for (int nt = 0; nt < 6; nt++) {
      int n = g * 192 + wn * 96 + nt * 16 + l16;
      int w = n >> 7;
      int d = n & 127;
      int t0 = m0 + wm * 32 + mt * 16 + quad * 4;
      if (w == 0) {
#pragma unroll
        for (int r = 0; r < 4; r++) Qb[(size_t)(t0 + r) * D_ + d] = f2b(acc[mt][nt][r]);
      } else if (w == 1) {
#pragma unroll
        for (int r = 0; r < 4; r++) Kb[(size_t)(t0 + r) * D_ + d] = f2b(acc[mt][nt][r]);
      } else {
        int b = t0 >> 11;
        int t = t0 & (T_ - 1);
        short4v pv;
        pv.x = (short)f2b(acc[mt][nt][0]); pv.y = (short)f2b(acc[mt][nt][1]);
        pv.z = (short)f2b(acc[mt][nt][2]); pv.w = (short)f2b(acc[mt][nt][3]);
        *(short4v*)&Vt[((size_t)(b * D_ + d)) * T_ + t] = pv;
      }
    }
}

// ---------------------------------------------------------------------------
// Kernel 3: causal flash attention. 512 blocks x 128 thr (2 waves).
// Block = (batch, 32-q tile), longest-first. The 2 waves SHARE one
// cooperatively staged K/V 64-kv chunk; wave w consumes kv sub-tile
// [32w,32w+32) (flash-decode inside the block), partials merged once via LDS
// at the end (verified r4 machinery). 42 KB LDS -> 3 blocks/CU: sibling
// blocks cover barrier drains. Fully-masked sub-tiles skip compute.
// S^T = K.Q^T (32x32x16): q-row lives in lanes {q,q+32} -> 1 shfl_xor.
// ---------------------------------------------------------------------------
#define PLD2 72

__global__ __launch_bounds__(128) void attn_kernel(
    const unsigned short* __restrict__ Qb, const unsigned short* __restrict__ Kb,
    const unsigned short* __restrict__ Vt, float* __restrict__ Out) {
  __shared__ __align__(16) unsigned short Ks[64 * 128];      // 16 KB (swizzled)
  __shared__ __align__(16) unsigned short Vs[128 * 64];      // 16 KB (V^T, swizzled)
  __shared__ __align__(16) unsigned short PsBuf[2][32 * PLD2];  // 9.2 KB
  __shared__ float Ms[32], Ls[32];

  const int tid = threadIdx.x;
  const int wv = tid >> 6;
  const int lane = tid & 63;
  const int l32 = lane & 31;
  const int hi = lane >> 5;

  const int batch = blockIdx.x & 7;
  const int qt = 63 - (blockIdx.x >> 3);  // longest-first (LPT)
  const int qb = qt * 32;

  unsigned short* Ps = &PsBuf[wv][0];
  const unsigned short* Kg = Kb + (size_t)batch * T_ * D_;
  const unsigned short* Vg = Vt + (size_t)batch * D_ * T_;
  const int qg = qb + l32;

  // Q B-frags from global: B[k][n]: n=l32 (q), k=kf*16+hi*8+j
  short8 qf[8];
#pragma unroll
  for (int kf = 0; kf < 8; kf++)
    qf[kf] = *(const short8*)(Qb + ((size_t)batch * T_ + qg) * D_ + kf * 16 + hi * 8);

  floatx16 oacc[4];  // O^T: col q=l32, row d=dt*32+(r&3)+8*(r>>2)+4*hi
#pragma unroll
  for (int dt = 0; dt < 4; dt++)
#pragma unroll
    for (int r = 0; r < 16; r++) oacc[dt][r] = 0.f;
  float mval = -1e30f, lval = 0.f;

  const int niter = qt / 2 + 1;  // ceil((qb+32)/64)
  for (int it = 0; it < niter; it++) {
    const int kb = it * 64;
    // cooperative staging: K 64x128 (8 glds/wave) + V^T 128x64 (8 glds/wave)
#pragma unroll
    for (int j = 0; j < 8; j++) {
      int rbase = wv * 32 + j * 4;
      int row = rbase + (lane >> 4);
      int gseg = (lane & 15) ^ (row & 15);
      gl_lds16(Kg + (size_t)(kb + row) * D_ + gseg * 8, &Ks[rbase * 128]);
    }
#pragma unroll
    for (int j = 0; j < 8; j++) {
      int rbase = wv * 64 + j * 8;
      int row = rbase + (lane >> 3);
      int gseg = (lane & 7) ^ (row & 7);
      gl_lds16(Vg + (size_t)row * T_ + kb + gseg * 8, &Vs[rbase * 64]);
    }
    __syncthreads();  // staging complete & visible to both waves

    const int kvb = kb + wv * 32;           // this wave's kv sub-tile base
    const bool active = kvb <= qb + 31;     // wave-uniform: any unmasked kv?
    if (active) {
      // S^T[kv][q]: A = K rows (m=kv32), B = qf. 8 MFMA.
      floatx16 sacc;
#pragma unroll
      for (int r = 0; r < 16; r++) sacc[r] = 0.f;
#pragma unroll
      for (int kf = 0; kf < 8; kf++) {
        short8 kfr = *(const short8*)&Ks[(wv * 32 + l32) * 128 +
                                         ((kf * 2 + hi) ^ (lane & 15)) * 8];
        sacc = __builtin_amdgcn_mfma_f32_32x32x16_bf16(kfr, qf[kf], sacc, 0, 0, 0);
      }
      // causal mask: kv = kvb + (r&3)+8*(r>>2)+4*hi
      if (kvb + 31 > qb) {
#pragma unroll
        for (int r = 0; r < 16; r++) {
          int kv = kvb + (r & 3) + 8 * (r >> 2) + 4 * hi;
          if (kv > qg) sacc[r] = -1e30f;
        }
      }
      // online softmax: 16 in-lane + 1 shfl_xor(32)
      float mx = -1e30f;
#pragma unroll
      for (int r = 0; r < 16; r++) mx = fmaxf(mx, sacc[r]);
      mx = fmaxf(mx, __shfl_xor(mx, 32, 64));
      float mnew = fmaxf(mval, mx);
      float alpha = EXP2F(mval - mnew);
      mval = mnew;
      float ps = 0.f;
#pragma unroll
      for (int r = 0; r < 16; r++) {
        float p = EXP2F(sacc[r] - mnew);
        sacc[r] = p;
        ps += p;
      }
      ps += __shfl_xor(ps, 32, 64);
      lval = lval * alpha + ps;
#pragma unroll
      for (int dt = 0; dt < 4; dt++)
#pragma unroll
        for (int r = 0; r < 16; r++) oacc[dt][r] *= alpha;

      // P -> LDS (C/D -> B-layout), per-wave private, same-wave DS in order
#pragma unroll
      for (int rg = 0; rg < 4; rg++) {
        short4v pk;
        pk.x = (short)f2b(sacc[rg * 4 + 0]);
        pk.y = (short)f2b(sacc[rg * 4 + 1]);
        pk.z = (short)f2b(sacc[rg * 4 + 2]);
        pk.w = (short)f2b(sacc[rg * 4 + 3]);
        *(short4v*)&Ps[l32 * PLD2 + 8 * rg + 4 * hi] = pk;
      }
      // O^T += V^T.P over this wave's 32 kv: kf2 x dt4 = 8 MFMA
#pragma unroll
      for (int kf = 0; kf < 2; kf++) {
        short8 pf = *(const short8*)&Ps[l32 * PLD2 + kf * 16 + hi * 8];
#pragma unroll
        for (int dt = 0; dt < 4; dt++) {
          int vrow = dt * 32 + l32;
          int vslot = (wv * 4 + kf * 2 + hi) ^ (vrow & 7);
          short8 vf = *(const short8*)&Vs[vrow * 64 + vslot * 8];
          oacc[dt] = __builtin_amdgcn_mfma_f32_32x32x16_bf16(vf, pf, oacc[dt], 0, 0, 0);
        }
      }
    }
    __syncthreads();  // all reads of Ks/Vs done before next staging
  }

  // cross-wave merge: wave1 publishes (m,l,O) via LDS overlay on Ks; wave0
  // combines and stores. (r4-verified.)
  float* Om = (float*)Ks;  // 128 x 32 floats = 16 KB
  if (wv == 1) {
    if (hi == 0) { Ms[l32] = mval; Ls[l32] = lval; }
#pragma unroll
    for (int dt = 0; dt < 4; dt++)
#pragma unroll
      for (int r = 0; r < 16; r++) {
        int d = dt * 32 + (r & 3) + 8 * (r >> 2) + 4 * hi;
        Om[d * 32 + l32] = oacc[dt][r];
      }
  }
  __syncthreads();
  if (wv == 0) {
    float m1 = Ms[l32], l1 = Ls[l32];
    float mstar = fmaxf(mval, m1);
    float a0 = EXP2F(mval - mstar);
    float a1 = EXP2F(m1 - mstar);
    float linv = 1.f / (lval * a0 + l1 * a1);
    float* Og = Out + ((size_t)batch * T_ + qg) * D_;
#pragma unroll
    for (int dt = 0; dt < 4; dt++)
#pragma unroll
      for (int rg = 0; rg < 4; rg++) {
        int dbase = dt * 32 + 8 * rg + 4 * hi;
        float4 o;
        o.x = (oacc[dt][rg * 4 + 0] * a0 + Om[(dbase + 0) * 32 + l32] * a1) * linv;
        o.y = (oacc[dt][rg * 4 + 1] * a0 + Om[(dbase + 1) * 32 + l32] * a1) * linv;
        o.z = (oacc[dt][rg * 4 + 2] * a0 + Om[(dbase + 2) * 32 + l32] * a1) * linv;
        o.w = (oacc[dt][rg * 4 + 3] * a0 + Om[(dbase + 3) * 32 + l32] * a1) * linv;
        *(float4*)&Og[dbase] = o;
      }
  }
}

// ---------------------------------------------------------------------------
extern "C" void kernel_launch(void* const* d_in, const int* in_sizes, int n_in,
                              void* d_out, int out_size, void* d_ws, size_t ws_size,
                              hipStream_t stream) {
  const float* X  = (const float*)d_in[0];
  const float* Wq = (const float*)d_in[1];
  const float* Wk = (const float*)d_in[2];
  const float* Wv = (const float*)d_in[3];
  float* Out = (float*)d_out;

  char* ws = (char*)d_ws;
  unsigned short* Wt3 = (unsigned short*)(ws);                        // 768 KB
  unsigned short* Qb  = (unsigned short*)(ws + 786432);               // 4 MB
  unsigned short* Kb  = (unsigned short*)(ws + 786432 + 4194304);     // 4 MB
  unsigned short* Vt  = (unsigned short*)(ws + 786432 + 2 * 4194304); // 4 MB

  hipLaunchKernelGGL(wtrans_kernel, dim3(96), dim3(256), 0, stream, Wq, Wk, Wv, Wt3);
  hipLaunchKernelGGL(qkv_kernel, dim3(512), dim3(256), 0, stream, X, Wt3, Qb, Kb, Vt);
  hipLaunchKernelGGL(attn_kernel, dim3(512), dim3(128), 0, stream, Qb, Kb, Vt, Out);
}

// Round 6
// 171.867 us; speedup vs baseline: 1.0238x; 1.0238x over previous
//
#include <hip/hip_runtime.h>
#include <hip/hip_bf16.h>

#define B_ 8
#define T_ 2048
#define E_ 1024
#define D_ 128

typedef __attribute__((ext_vector_type(8))) short short8;
typedef __attribute__((ext_vector_type(4))) short short4v;
typedef __attribute__((ext_vector_type(4))) float floatx4;
typedef __attribute__((ext_vector_type(16))) float floatx16;

__device__ __forceinline__ unsigned short f2b(float f) {
  union { float f; unsigned int u; } v; v.f = f;
  unsigned int u = v.u;
  return (unsigned short)((u + 0x7fffu + ((u >> 16) & 1u)) >> 16);  // RNE
}

#if defined(__has_builtin)
#if __has_builtin(__builtin_amdgcn_exp2f)
#define EXP2F(x) __builtin_amdgcn_exp2f(x)
#else
#define EXP2F(x) exp2f(x)
#endif
#else
#define EXP2F(x) exp2f(x)
#endif

__device__ __forceinline__ void gl_lds16(const unsigned short* g, unsigned short* l) {
  __builtin_amdgcn_global_load_lds(
      (const __attribute__((address_space(1))) unsigned int*)g,
      (__attribute__((address_space(3))) unsigned int*)l, 16, 0, 0);
}

// ---------------------------------------------------------------------------
// Kernel 1: W [1024x128] fp32 -> Wt3 [3][128][1024] bf16 via LDS transpose.
// log2e/sqrt(128) folded into Wq (attn softmax then uses exp2 directly).
// ---------------------------------------------------------------------------
__global__ __launch_bounds__(256) void wtrans_kernel(
    const float* __restrict__ Wq, const float* __restrict__ Wk,
    const float* __restrict__ Wv, unsigned short* __restrict__ Wt3) {
  __shared__ __align__(16) unsigned short Tls[32][136];
  const int tid = threadIdx.x;
  const int w = blockIdx.x >> 5;
  const int rem = blockIdx.x & 31;
  const int k0 = (rem >> 2) * 128;
  const int n0 = (rem & 3) * 32;
  const float* W = (w == 0) ? Wq : ((w == 1) ? Wk : Wv);
  const float scale = (w == 0) ? (1.4426950408889634f * 0.08838834764831845f) : 1.0f;
#pragma unroll
  for (int j = 0; j < 4; j++) {
    int id = tid + 256 * j;
    int k = id >> 3;
    int nn = (id & 7) * 4;
    float4 v = *(const float4*)(W + (size_t)(k0 + k) * D_ + n0 + nn);
    Tls[nn + 0][k] = f2b(v.x * scale);
    Tls[nn + 1][k] = f2b(v.y * scale);
    Tls[nn + 2][k] = f2b(v.z * scale);
    Tls[nn + 3][k] = f2b(v.w * scale);
  }
  __syncthreads();
#pragma unroll
  for (int j = 0; j < 2; j++) {
    int id = tid + 256 * j;
    int n = id >> 4;
    int seg = id & 15;
    short8 o = *(const short8*)&Tls[n][seg * 8];
    *(short8*)&Wt3[(size_t)w * D_ * E_ + (size_t)(n0 + n) * E_ + k0 + seg * 8] = o;
  }
}

// ---------------------------------------------------------------------------
// Kernel 2: fused QKV (r5 structure). Tile 64 tok x 192 ch, BK=64, 16 iters;
// grid 512 x 256 thr, 34 KB LDS -> 4 blocks/CU.
// ---------------------------------------------------------------------------
#define XLD 72  // 64 + 8 pad (shorts)

__global__ __launch_bounds__(256) void qkv_kernel(
    const float* __restrict__ X, const unsigned short* __restrict__ Wt3,
    unsigned short* __restrict__ Qb, unsigned short* __restrict__ Kb,
    unsigned short* __restrict__ Vt) {
  __shared__ __align__(16) unsigned short Xs[64 * XLD];   // 9.2 KB
  __shared__ __align__(16) unsigned short Ws[192 * 64];   // 24 KB swizzled
  const int tid = threadIdx.x;
  const int wv = tid >> 6;
  const int lane = tid & 63;
  const int l16 = lane & 15;
  const int quad = lane >> 4;
  const int wm = wv & 1;
  const int wn = wv >> 1;

  const int g = blockIdx.x & 1;
  const int m0 = (blockIdx.x >> 1) * 64;
  const unsigned short* Wg = Wt3 + (size_t)g * 192 * E_;

  const int xrow = tid >> 2;
  const int xq = (tid & 3) * 16;
  const int wrow_off = lane >> 3;
  const int wslot = lane & 7;

  floatx4 acc[2][6];
#pragma unroll
  for (int mt = 0; mt < 2; mt++)
#pragma unroll
    for (int nt = 0; nt < 6; nt++) acc[mt][nt] = (floatx4){0.f, 0.f, 0.f, 0.f};

  float4 xr[4];
#pragma unroll
  for (int c = 0; c < 4; c++)
    xr[c] = *(const float4*)(X + (size_t)(m0 + xrow) * E_ + xq + c * 4);

  for (int i = 0; i < 16; i++) {
    if (i) __syncthreads();
    const int k0 = i * 64;
#pragma unroll
    for (int c = 0; c < 4; c++) {
      ushort4 pk;
      pk.x = f2b(xr[c].x); pk.y = f2b(xr[c].y);
      pk.z = f2b(xr[c].z); pk.w = f2b(xr[c].w);
      *(ushort4*)&Xs[xrow * XLD + xq + c * 4] = pk;
    }
#pragma unroll
    for (int j = 0; j < 6; j++) {
      int rbase = wv * 48 + j * 8;
      int row = rbase + wrow_off;
      int gseg = wslot ^ (row & 7);
      gl_lds16(Wg + (size_t)row * E_ + k0 + gseg * 8, &Ws[rbase * 64]);
    }
    __syncthreads();
    if (i < 15) {
#pragma unroll
      for (int c = 0; c < 4; c++)
        xr[c] = *(const float4*)(X + (size_t)(m0 + xrow) * E_ + k0 + 64 + xq + c * 4);
    }
    short8 af[2][2];
#pragma unroll
    for (int mt = 0; mt < 2; mt++)
#pragma unroll
      for (int kf = 0; kf < 2; kf++)
        af[mt][kf] = *(const short8*)&Xs[(wm * 32 + mt * 16 + l16) * XLD + kf * 32 + quad * 8];
#pragma unroll
    for (int nt = 0; nt < 6; nt++) {
      int n = wn * 96 + nt * 16 + l16;
#pragma unroll
      for (int kf = 0; kf < 2; kf++) {
        short8 bf = *(const short8*)&Ws[n * 64 + ((kf * 4 + quad) ^ (n & 7)) * 8];
        acc[0][nt] = __builtin_amdgcn_mfma_f32_16x16x32_bf16(af[0][kf], bf, acc[0][nt], 0, 0, 0);
        acc[1][nt] = __builtin_amdgcn_mfma_f32_16x16x32_bf16(af[1][kf], bf, acc[1][nt], 0, 0, 0);
      }
    }
  }

#pragma unroll
  for (int mt = 0; mt < 2; mt++)
#pragma unroll
    for (int nt = 0; nt < 6; nt++) {
      int n = g * 192 + wn * 96 + nt * 16 + l16;
      int w = n >> 7;
      int d = n & 127;
      int t0 = m0 + wm * 32 + mt * 16 + quad * 4;
      if (w == 0) {
#pragma unroll
        for (int r = 0; r < 4; r++) Qb[(size_t)(t0 + r) * D_ + d] = f2b(acc[mt][nt][r]);
      } else if (w == 1) {
#pragma unroll
        for (int r = 0; r < 4; r++) Kb[(size_t)(t0 + r) * D_ + d] = f2b(acc[mt][nt][r]);
      } else {
        int b = t0 >> 11;
        int t = t0 & (T_ - 1);
        short4v pv;
        pv.x = (short)f2b(acc[mt][nt][0]); pv.y = (short)f2b(acc[mt][nt][1]);
        pv.z = (short)f2b(acc[mt][nt][2]); pv.w = (short)f2b(acc[mt][nt][3]);
        *(short4v*)&Vt[((size_t)(b * D_ + d)) * T_ + t] = pv;
      }
    }
}

// ---------------------------------------------------------------------------
// Kernel 3: causal flash attention — REGISTER-DIRECT, BARRIER-FREE K-loop.
// 512 blocks x 256 thr (4 waves), block = (batch, 32-q tile), LPT order.
// Wave w processes 32-kv chunks it = w, w+4, ... (<= qt); K/V fragments load
// straight from global into VGPRs (no LDS staging, no __syncthreads in loop).
// S^T = K.Q^T (32x32x16): q-row in lanes {q,q+32} -> 1 shfl_xor per reduce.
// P C/D->B-operand transform in-register via 8 shfl_xor(32) (derived lane
// mapping: hi=0 {q0,q1,x0,x1}, hi=1 {x2,x3,q2,q3}; +4 offset for k2=1).
// End: 4 partials merged via LDS (r4-verified machinery, 3 publishers).
// __launch_bounds__(256,2) -> 8 waves/CU co-resident for TLP.
// ---------------------------------------------------------------------------
__global__ __launch_bounds__(256, 2) void attn_kernel(
    const unsigned short* __restrict__ Qb, const unsigned short* __restrict__ Kb,
    const unsigned short* __restrict__ Vt, float* __restrict__ Out) {
  __shared__ float Om[3][128][32];  // 48 KB merge buffer
  __shared__ float Ms[4][32], Ls[4][32];

  const int tid = threadIdx.x;
  const int wv = tid >> 6;
  const int lane = tid & 63;
  const int l32 = lane & 31;
  const int hi = lane >> 5;

  const int batch = blockIdx.x & 7;
  const int qt = 63 - (blockIdx.x >> 3);  // longest-first
  const int qb = qt * 32;
  const int qg = qb + l32;

  const unsigned short* Kg = Kb + (size_t)batch * T_ * D_;
  const unsigned short* Vg = Vt + (size_t)batch * D_ * T_;

  // Q B-frags from global: B[k][n]: n=l32 (q), k=kf*16+hi*8+j
  short8 qf[8];
#pragma unroll
  for (int kf = 0; kf < 8; kf++)
    qf[kf] = *(const short8*)(Qb + ((size_t)batch * T_ + qg) * D_ + kf * 16 + hi * 8);

  floatx16 oacc[4];  // O^T: col q=l32, row d=dt*32+(r&3)+8*(r>>2)+4*hi
#pragma unroll
  for (int dt = 0; dt < 4; dt++)
#pragma unroll
    for (int r = 0; r < 16; r++) oacc[dt][r] = 0.f;
  float mval = -1e30f, lval = 0.f;

  for (int it = wv; it <= qt; it += 4) {
    const int kb = it * 32;
    // K frags (A of S^T): m=kv=kb+l32, k=d -> 8 x 16B direct global
    short8 kfr[8];
#pragma unroll
    for (int kf = 0; kf < 8; kf++)
      kfr[kf] = *(const short8*)(Kg + (size_t)(kb + l32) * D_ + kf * 16 + hi * 8);
    // V frags (A of O^T += V^T.P): m=d=dt*32+l32, k=kv_local
    short8 vfr[4][2];
#pragma unroll
    for (int dt = 0; dt < 4; dt++)
#pragma unroll
      for (int k2 = 0; k2 < 2; k2++)
        vfr[dt][k2] = *(const short8*)(Vg + (size_t)(dt * 32 + l32) * T_ + kb + k2 * 16 + hi * 8);

    // S^T[kv][q], 32x32, K-dim 128: 8 MFMA
    floatx16 sacc;
#pragma unroll
    for (int r = 0; r < 16; r++) sacc[r] = 0.f;
#pragma unroll
    for (int kf = 0; kf < 8; kf++)
      sacc = __builtin_amdgcn_mfma_f32_32x32x16_bf16(kfr[kf], qf[kf], sacc, 0, 0, 0);

    // causal mask: only the diagonal chunk (it==qt) is partial
    if (it == qt) {
#pragma unroll
      for (int r = 0; r < 16; r++) {
        int kv = kb + (r & 3) + 8 * (r >> 2) + 4 * hi;
        if (kv > qg) sacc[r] = -1e30f;
      }
    }

    // online softmax: 16 in-lane + 1 shfl_xor(32) each for max and sum
    float mx = -1e30f;
#pragma unroll
    for (int r = 0; r < 16; r++) mx = fmaxf(mx, sacc[r]);
    mx = fmaxf(mx, __shfl_xor(mx, 32, 64));
    float mnew = fmaxf(mval, mx);
    float alpha = EXP2F(mval - mnew);
    mval = mnew;
    float ps = 0.f;
#pragma unroll
    for (int r = 0; r < 16; r++) {
      float p = EXP2F(sacc[r] - mnew);
      sacc[r] = p;
      ps += p;
    }
    ps += __shfl_xor(ps, 32, 64);
    lval = lval * alpha + ps;
#pragma unroll
    for (int dt = 0; dt < 4; dt++)
#pragma unroll
      for (int r = 0; r < 16; r++) oacc[dt][r] *= alpha;

    // P: C/D -> B-operand, in-register. kv(r,hi) = (r&3)+8*(r>>2)+4*hi.
    // Pack adjacent-kv pairs, swap halves of the wave via shfl_xor(32).
    unsigned int qp[8], xp[8];
#pragma unroll
    for (int i = 0; i < 8; i++)
      qp[i] = (unsigned int)f2b(sacc[2 * i]) |
              ((unsigned int)f2b(sacc[2 * i + 1]) << 16);
#pragma unroll
    for (int i = 0; i < 8; i++)
      xp[i] = (unsigned int)__shfl_xor((int)qp[i], 32, 64);
    union { short8 s; unsigned int u[4]; } pf0, pf1;
    pf0.u[0] = hi ? xp[2] : qp[0];
    pf0.u[1] = hi ? xp[3] : qp[1];
    pf0.u[2] = hi ? qp[2] : xp[0];
    pf0.u[3] = hi ? qp[3] : xp[1];
    pf1.u[0] = hi ? xp[6] : qp[4];
    pf1.u[1] = hi ? xp[7] : qp[5];
    pf1.u[2] = hi ? qp[6] : xp[4];
    pf1.u[3] = hi ? qp[7] : xp[5];

    // O^T += V^T.P: 4 dt x 2 k2 = 8 MFMA
#pragma unroll
    for (int dt = 0; dt < 4; dt++) {
      oacc[dt] = __builtin_amdgcn_mfma_f32_32x32x16_bf16(vfr[dt][0], pf0.s, oacc[dt], 0, 0, 0);
      oacc[dt] = __builtin_amdgcn_mfma_f32_32x32x16_bf16(vfr[dt][1], pf1.s, oacc[dt], 0, 0, 0);
    }
  }

  // merge 4 partials: waves 1-3 publish (m,l,O) to LDS; wave 0 combines.
  if (wv) {
    if (hi == 0) { Ms[wv][l32] = mval; Ls[wv][l32] = lval; }
#pragma unroll
    for (int dt = 0; dt < 4; dt++)
#pragma unroll
      for (int r = 0; r < 16; r++) {
        int d = dt * 32 + (r & 3) + 8 * (r >> 2) + 4 * hi;
        Om[wv - 1][d][l32] = oacc[dt][r];
      }
  }
  __syncthreads();
  if (wv == 0) {
    float m1 = Ms[1][l32], m2 = Ms[2][l32], m3 = Ms[3][l32];
    float l1 = Ls[1][l32], l2 = Ls[2][l32], l3 = Ls[3][l32];
    float mstar = fmaxf(fmaxf(mval, m1), fmaxf(m2, m3));
    float a0 = EXP2F(mval - mstar);
    float a1 = EXP2F(m1 - mstar);
    float a2 = EXP2F(m2 - mstar);
    float a3 = EXP2F(m3 - mstar);
    float linv = 1.f / (lval * a0 + l1 * a1 + l2 * a2 + l3 * a3);
    float* Og = Out + ((size_t)batch * T_ + qg) * D_;
#pragma unroll
    for (int dt = 0; dt < 4; dt++)
#pragma unroll
      for (int rg = 0; rg < 4; rg++) {
        int dbase = dt * 32 + 8 * rg + 4 * hi;
        float4 o;
#pragma unroll
        for (int c = 0; c < 4; c++) {
          float v = oacc[dt][rg * 4 + c] * a0 +
                    Om[0][dbase + c][l32] * a1 +
                    Om[1][dbase + c][l32] * a2 +
                    Om[2][dbase + c][l32] * a3;
          ((float*)&o)[c] = v * linv;
        }
        *(float4*)&Og[dbase] = o;
      }
  }
}

// ---------------------------------------------------------------------------
extern "C" void kernel_launch(void* const* d_in, const int* in_sizes, int n_in,
                              void* d_out, int out_size, void* d_ws, size_t ws_size,
                              hipStream_t stream) {
  const float* X  = (const float*)d_in[0];
  const float* Wq = (const float*)d_in[1];
  const float* Wk = (const float*)d_in[2];
  const float* Wv = (const float*)d_in[3];
  float* Out = (float*)d_out;

  char* ws = (char*)d_ws;
  unsigned short* Wt3 = (unsigned short*)(ws);                        // 768 KB
  unsigned short* Qb  = (unsigned short*)(ws + 786432);               // 4 MB
  unsigned short* Kb  = (unsigned short*)(ws + 786432 + 4194304);     // 4 MB
  unsigned short* Vt  = (unsigned short*)(ws + 786432 + 2 * 4194304); // 4 MB

  hipLaunchKernelGGL(wtrans_kernel, dim3(96), dim3(256), 0, stream, Wq, Wk, Wv, Wt3);
  hipLaunchKernelGGL(qkv_kernel, dim3(512), dim3(256), 0, stream, X, Wt3, Qb, Kb, Vt);
  hipLaunchKernelGGL(attn_kernel, dim3(512), dim3(256), 0, stream, Qb, Kb, Vt, Out);
}

// Round 7
// 144.469 us; speedup vs baseline: 1.2180x; 1.1896x over previous
//
#include <hip/hip_runtime.h>
#include <hip/hip_bf16.h>

#define B_ 8
#define T_ 2048
#define E_ 1024
#define D_ 128

typedef __attribute__((ext_vector_type(8))) short short8;
typedef __attribute__((ext_vector_type(4))) short short4v;
typedef __attribute__((ext_vector_type(4))) float floatx4;
typedef __attribute__((ext_vector_type(16))) float floatx16;

__device__ __forceinline__ unsigned short f2b(float f) {
  union { float f; unsigned int u; } v; v.f = f;
  unsigned int u = v.u;
  return (unsigned short)((u + 0x7fffu + ((u >> 16) & 1u)) >> 16);  // RNE
}

#if defined(__has_builtin)
#if __has_builtin(__builtin_amdgcn_exp2f)
#define EXP2F(x) __builtin_amdgcn_exp2f(x)
#else
#define EXP2F(x) exp2f(x)
#endif
#else
#define EXP2F(x) exp2f(x)
#endif

__device__ __forceinline__ void gl_lds16(const unsigned short* g, unsigned short* l) {
  __builtin_amdgcn_global_load_lds(
      (const __attribute__((address_space(1))) unsigned int*)g,
      (__attribute__((address_space(3))) unsigned int*)l, 16, 0, 0);
}

// ---------------------------------------------------------------------------
// Kernel 1: W [1024x128] fp32 -> Wt3 [3][128][1024] bf16 via LDS transpose.
// log2e/sqrt(128) folded into Wq (attn softmax then uses exp2 directly).
// ---------------------------------------------------------------------------
__global__ __launch_bounds__(256) void wtrans_kernel(
    const float* __restrict__ Wq, const float* __restrict__ Wk,
    const float* __restrict__ Wv, unsigned short* __restrict__ Wt3) {
  __shared__ __align__(16) unsigned short Tls[32][136];
  const int tid = threadIdx.x;
  const int w = blockIdx.x >> 5;
  const int rem = blockIdx.x & 31;
  const int k0 = (rem >> 2) * 128;
  const int n0 = (rem & 3) * 32;
  const float* W = (w == 0) ? Wq : ((w == 1) ? Wk : Wv);
  const float scale = (w == 0) ? (1.4426950408889634f * 0.08838834764831845f) : 1.0f;
#pragma unroll
  for (int j = 0; j < 4; j++) {
    int id = tid + 256 * j;
    int k = id >> 3;
    int nn = (id & 7) * 4;
    float4 v = *(const float4*)(W + (size_t)(k0 + k) * D_ + n0 + nn);
    Tls[nn + 0][k] = f2b(v.x * scale);
    Tls[nn + 1][k] = f2b(v.y * scale);
    Tls[nn + 2][k] = f2b(v.z * scale);
    Tls[nn + 3][k] = f2b(v.w * scale);
  }
  __syncthreads();
#pragma unroll
  for (int j = 0; j < 2; j++) {
    int id = tid + 256 * j;
    int n = id >> 4;
    int seg = id & 15;
    short8 o = *(const short8*)&Tls[n][seg * 8];
    *(short8*)&Wt3[(size_t)w * D_ * E_ + (size_t)(n0 + n) * E_ + k0 + seg * 8] = o;
  }
}

// ---------------------------------------------------------------------------
// Kernel 2: fused QKV (r5 loop structure). Tile 64 tok x 192 ch, BK=64,
// 16 iters; grid 512 x 256 thr, 34 KB LDS -> 4 blocks/CU.
// NEW epilogue: outputs in MFMA-FRAGMENT-PACKED layouts so attn's frag loads
// are base+lane*16 (perfectly coalesced):
//   Qf/Kf: [b][tile32][kf=d/16][lane=hi*32+l32][j]  (lane: l32=t&31, hi=(d>>3)&1, j=d&7)
//   Vf:    [b][tile32][f=k2*4+dt][lane=hi*32+l32][j] (l32=d&31, hi=(t>>3)&1, j=t&7)
// ---------------------------------------------------------------------------
#define XLD 72  // 64 + 8 pad (shorts)

__global__ __launch_bounds__(256) void qkv_kernel(
    const float* __restrict__ X, const unsigned short* __restrict__ Wt3,
    unsigned short* __restrict__ Qf, unsigned short* __restrict__ Kf,
    unsigned short* __restrict__ Vf) {
  __shared__ __align__(16) unsigned short Xs[64 * XLD];   // 9.2 KB
  __shared__ __align__(16) unsigned short Ws[192 * 64];   // 24 KB swizzled
  const int tid = threadIdx.x;
  const int wv = tid >> 6;
  const int lane = tid & 63;
  const int l16 = lane & 15;
  const int quad = lane >> 4;
  const int wm = wv & 1;
  const int wn = wv >> 1;

  const int g = blockIdx.x & 1;
  const int m0 = (blockIdx.x >> 1) * 64;
  const unsigned short* Wg = Wt3 + (size_t)g * 192 * E_;

  const int xrow = tid >> 2;
  const int xq = (tid & 3) * 16;
  const int wrow_off = lane >> 3;
  const int wslot = lane & 7;

  floatx4 acc[2][6];
#pragma unroll
  for (int mt = 0; mt < 2; mt++)
#pragma unroll
    for (int nt = 0; nt < 6; nt++) acc[mt][nt] = (floatx4){0.f, 0.f, 0.f, 0.f};

  float4 xr[4];
#pragma unroll
  for (int c = 0; c < 4; c++)
    xr[c] = *(const float4*)(X + (size_t)(m0 + xrow) * E_ + xq + c * 4);

  for (int i = 0; i < 16; i++) {
    if (i) __syncthreads();
    const int k0 = i * 64;
#pragma unroll
    for (int c = 0; c < 4; c++) {
      ushort4 pk;
      pk.x = f2b(xr[c].x); pk.y = f2b(xr[c].y);
      pk.z = f2b(xr[c].z); pk.w = f2b(xr[c].w);
      *(ushort4*)&Xs[xrow * XLD + xq + c * 4] = pk;
    }
#pragma unroll
    for (int j = 0; j < 6; j++) {
      int rbase = wv * 48 + j * 8;
      int row = rbase + wrow_off;
      int gseg = wslot ^ (row & 7);
      gl_lds16(Wg + (size_t)row * E_ + k0 + gseg * 8, &Ws[rbase * 64]);
    }
    __syncthreads();
    if (i < 15) {
#pragma unroll
      for (int c = 0; c < 4; c++)
        xr[c] = *(const float4*)(X + (size_t)(m0 + xrow) * E_ + k0 + 64 + xq + c * 4);
    }
    short8 af[2][2];
#pragma unroll
    for (int mt = 0; mt < 2; mt++)
#pragma unroll
      for (int kf = 0; kf < 2; kf++)
        af[mt][kf] = *(const short8*)&Xs[(wm * 32 + mt * 16 + l16) * XLD + kf * 32 + quad * 8];
#pragma unroll
    for (int nt = 0; nt < 6; nt++) {
      int n = wn * 96 + nt * 16 + l16;
#pragma unroll
      for (int kf = 0; kf < 2; kf++) {
        short8 bf = *(const short8*)&Ws[n * 64 + ((kf * 4 + quad) ^ (n & 7)) * 8];
        acc[0][nt] = __builtin_amdgcn_mfma_f32_16x16x32_bf16(af[0][kf], bf, acc[0][nt], 0, 0, 0);
        acc[1][nt] = __builtin_amdgcn_mfma_f32_16x16x32_bf16(af[1][kf], bf, acc[1][nt], 0, 0, 0);
      }
    }
  }

  // Epilogue -> fragment-packed outputs. C/D: col(n)=l16, row(m)=quad*4+r.
#pragma unroll
  for (int mt = 0; mt < 2; mt++)
#pragma unroll
    for (int nt = 0; nt < 6; nt++) {
      int n = g * 192 + wn * 96 + nt * 16 + l16;
      int t0 = m0 + wm * 32 + mt * 16 + quad * 4;
      int b = t0 >> 11;
      int tt0 = t0 & (T_ - 1);
      int tile = tt0 >> 5;
      if (n < 256) {
        unsigned short* Fg = (n < 128) ? Qf : Kf;
        int d = n & 127;
        int kf = d >> 4;
        int hi2 = (d >> 3) & 1;
        int j = d & 7;
        int l32b = tt0 & 31;  // + r
        size_t base = ((size_t)((b * 64 + tile) * 8 + kf)) * 512 + hi2 * 256 + j;
#pragma unroll
        for (int r = 0; r < 4; r++)
          Fg[base + (size_t)(l32b + r) * 8] = f2b(acc[mt][nt][r]);
      } else {
        int d = n - 256;
        int k2 = (tt0 >> 4) & 1;
        int hi2 = (tt0 >> 3) & 1;
        int jb = tt0 & 7;  // 0 or 4; +r contiguous
        int l32 = d & 31;
        int dt = d >> 5;
        short4v pv;
        pv.x = (short)f2b(acc[mt][nt][0]); pv.y = (short)f2b(acc[mt][nt][1]);
        pv.z = (short)f2b(acc[mt][nt][2]); pv.w = (short)f2b(acc[mt][nt][3]);
        size_t base = ((size_t)((b * 64 + tile) * 8 + k2 * 4 + dt)) * 512 +
                      (size_t)(hi2 * 32 + l32) * 8 + jb;
        *(short4v*)&Vf[base] = pv;
      }
    }
}

// ---------------------------------------------------------------------------
// Kernel 3: causal flash attention — frag-packed register-direct, barrier-free
// K-loop with MANUAL K-PREFETCH (ping-pong kA/kB one chunk ahead; V issued at
// iter start, consumed after softmax = self-hiding). All frag loads are
// base+lane*16: single coalesced 1KB transaction each (r6's stride-256B
// gathers eliminated). 512 blocks x 256 thr (4 waves); wave w owns chunks
// it = w, w+4, ...; end merge via LDS (r4/r6-verified machinery).
// ---------------------------------------------------------------------------
#define LOADK(DST, ITV)                                                      \
  _Pragma("unroll") for (int kf_ = 0; kf_ < 8; kf_++)                        \
      DST[kf_] = *(const short8*)(Kbase + (size_t)(ITV) * 4096 + kf_ * 512 + lane * 8);

#define LOADV(DST, ITV)                                                      \
  _Pragma("unroll") for (int f_ = 0; f_ < 8; f_++)                           \
      DST[f_] = *(const short8*)(Vbase + (size_t)(ITV) * 4096 + f_ * 512 + lane * 8);

#define ATTN_STEP(KFR, VFR, ITV)                                             \
  {                                                                          \
    floatx16 sacc;                                                           \
    _Pragma("unroll") for (int r = 0; r < 16; r++) sacc[r] = 0.f;            \
    _Pragma("unroll") for (int kf = 0; kf < 8; kf++)                         \
        sacc = __builtin_amdgcn_mfma_f32_32x32x16_bf16(KFR[kf], qf[kf], sacc, 0, 0, 0); \
    if ((ITV) == qt) {                                                       \
      _Pragma("unroll") for (int r = 0; r < 16; r++) {                       \
        int kv = (ITV) * 32 + (r & 3) + 8 * (r >> 2) + 4 * hi;               \
        if (kv > qg) sacc[r] = -1e30f;                                       \
      }                                                                      \
    }                                                                        \
    float mx = -1e30f;                                                       \
    _Pragma("unroll") for (int r = 0; r < 16; r++) mx = fmaxf(mx, sacc[r]);  \
    mx = fmaxf(mx, __shfl_xor(mx, 32, 64));                                  \
    float mnew = fmaxf(mval, mx);                                            \
    float alpha = EXP2F(mval - mnew);                                        \
    mval = mnew;                                                             \
    float ps = 0.f;                                                          \
    _Pragma("unroll") for (int r = 0; r < 16; r++) {                         \
      float p = EXP2F(sacc[r] - mnew);                                       \
      sacc[r] = p;                                                           \
      ps += p;                                                               \
    }                                                                        \
    ps += __shfl_xor(ps, 32, 64);                                            \
    lval = lval * alpha + ps;                                                \
    _Pragma("unroll") for (int dt = 0; dt < 4; dt++)                         \
        _Pragma("unroll") for (int r = 0; r < 16; r++) oacc[dt][r] *= alpha; \
    unsigned int qp[8], xp[8];                                               \
    _Pragma("unroll") for (int i = 0; i < 8; i++)                            \
        qp[i] = (unsigned int)f2b(sacc[2 * i]) |                             \
                ((unsigned int)f2b(sacc[2 * i + 1]) << 16);                  \
    _Pragma("unroll") for (int i = 0; i < 8; i++)                            \
        xp[i] = (unsigned int)__shfl_xor((int)qp[i], 32, 64);                \
    union { short8 s; unsigned int u[4]; } pf0, pf1;                         \
    pf0.u[0] = hi ? xp[2] : qp[0];                                           \
    pf0.u[1] = hi ? xp[3] : qp[1];                                           \
    pf0.u[2] = hi ? qp[2] : xp[0];                                           \
    pf0.u[3] = hi ? qp[3] : xp[1];                                           \
    pf1.u[0] = hi ? xp[6] : qp[4];                                           \
    pf1.u[1] = hi ? xp[7] : qp[5];                                           \
    pf1.u[2] = hi ? qp[6] : xp[4];                                           \
    pf1.u[3] = hi ? qp[7] : xp[5];                                           \
    _Pragma("unroll") for (int dt = 0; dt < 4; dt++) {                       \
      oacc[dt] = __builtin_amdgcn_mfma_f32_32x32x16_bf16(VFR[dt], pf0.s, oacc[dt], 0, 0, 0);     \
      oacc[dt] = __builtin_amdgcn_mfma_f32_32x32x16_bf16(VFR[4 + dt], pf1.s, oacc[dt], 0, 0, 0); \
    }                                                                        \
  }

__global__ __launch_bounds__(256, 2) void attn_kernel(
    const unsigned short* __restrict__ Qf, const unsigned short* __restrict__ Kf,
    const unsigned short* __restrict__ Vf, float* __restrict__ Out) {
  __shared__ float Om[3][128][32];  // 48 KB merge buffer
  __shared__ float Ms[4][32], Ls[4][32];

  const int tid = threadIdx.x;
  const int wv = tid >> 6;
  const int lane = tid & 63;
  const int l32 = lane & 31;
  const int hi = lane >> 5;

  const int batch = blockIdx.x & 7;
  const int qt = 63 - (blockIdx.x >> 3);  // longest-first
  const int qb = qt * 32;
  const int qg = qb + l32;

  const unsigned short* Kbase = Kf + (size_t)batch * 64 * 4096;
  const unsigned short* Vbase = Vf + (size_t)batch * 64 * 4096;

  // Q B-frags: coalesced base+lane*16
  short8 qf[8];
  const unsigned short* Qp = Qf + (size_t)(batch * 64 + qt) * 4096;
#pragma unroll
  for (int kf = 0; kf < 8; kf++)
    qf[kf] = *(const short8*)(Qp + kf * 512 + lane * 8);

  floatx16 oacc[4];  // O^T: col q=l32, row d=dt*32+(r&3)+8*(r>>2)+4*hi
#pragma unroll
  for (int dt = 0; dt < 4; dt++)
#pragma unroll
    for (int r = 0; r < 16; r++) oacc[dt][r] = 0.f;
  float mval = -1e30f, lval = 0.f;

  short8 kA[8], kB[8], vC[8];
  int it = wv;
  if (it <= qt) {
    LOADK(kA, it);
    while (true) {
      int nit = it + 4;
      LOADV(vC, it);
      if (nit <= qt) LOADK(kB, nit);
      ATTN_STEP(kA, vC, it);
      if (nit > qt) break;
      it = nit;
      nit = it + 4;
      LOADV(vC, it);
      if (nit <= qt) LOADK(kA, nit);
      ATTN_STEP(kB, vC, it);
      if (nit > qt) break;
      it = nit;
    }
  }

  // merge 4 partials: waves 1-3 publish (m,l,O) to LDS; wave 0 combines.
  if (wv) {
    if (hi == 0) { Ms[wv][l32] = mval; Ls[wv][l32] = lval; }
#pragma unroll
    for (int dt = 0; dt < 4; dt++)
#pragma unroll
      for (int r = 0; r < 16; r++) {
        int d = dt * 32 + (r & 3) + 8 * (r >> 2) + 4 * hi;
        Om[wv - 1][d][l32] = oacc[dt][r];
      }
  }
  __syncthreads();
  if (wv == 0) {
    float m1 = Ms[1][l32], m2 = Ms[2][l32], m3 = Ms[3][l32];
    float l1 = Ls[1][l32], l2 = Ls[2][l32], l3 = Ls[3][l32];
    float mstar = fmaxf(fmaxf(mval, m1), fmaxf(m2, m3));
    float a0 = EXP2F(mval - mstar);
    float a1 = EXP2F(m1 - mstar);
    float a2 = EXP2F(m2 - mstar);
    float a3 = EXP2F(m3 - mstar);
    float linv = 1.f / (lval * a0 + l1 * a1 + l2 * a2 + l3 * a3);
    float* Og = Out + ((size_t)batch * T_ + qg) * D_;
#pragma unroll
    for (int dt = 0; dt < 4; dt++)
#pragma unroll
      for (int rg = 0; rg < 4; rg++) {
        int dbase = dt * 32 + 8 * rg + 4 * hi;
        float4 o;
#pragma unroll
        for (int c = 0; c < 4; c++) {
          float v = oacc[dt][rg * 4 + c] * a0 +
                    Om[0][dbase + c][l32] * a1 +
                    Om[1][dbase + c][l32] * a2 +
                    Om[2][dbase + c][l32] * a3;
          ((float*)&o)[c] = v * linv;
        }
        *(float4*)&Og[dbase] = o;
      }
  }
}

// ---------------------------------------------------------------------------
extern "C" void kernel_launch(void* const* d_in, const int* in_sizes, int n_in,
                              void* d_out, int out_size, void* d_ws, size_t ws_size,
                              hipStream_t stream) {
  const float* X  = (const float*)d_in[0];
  const float* Wq = (const float*)d_in[1];
  const float* Wk = (const float*)d_in[2];
  const float* Wv = (const float*)d_in[3];
  float* Out = (float*)d_out;

  char* ws = (char*)d_ws;
  unsigned short* Wt3 = (unsigned short*)(ws);                        // 768 KB
  unsigned short* Qf  = (unsigned short*)(ws + 786432);               // 4 MB
  unsigned short* Kf  = (unsigned short*)(ws + 786432 + 4194304);     // 4 MB
  unsigned short* Vf  = (unsigned short*)(ws + 786432 + 2 * 4194304); // 4 MB

  hipLaunchKernelGGL(wtrans_kernel, dim3(96), dim3(256), 0, stream, Wq, Wk, Wv, Wt3);
  hipLaunchKernelGGL(qkv_kernel, dim3(512), dim3(256), 0, stream, X, Wt3, Qf, Kf, Vf);
  hipLaunchKernelGGL(attn_kernel, dim3(512), dim3(256), 0, stream, Qf, Kf, Vf, Out);
}